// Round 8
// baseline (101942.419 us; speedup 1.0000x reference)
//
#include <hip/hip_runtime.h>
#include <hip/hip_bf16.h>
#include <math.h>

#define NB 32
#define NKS 2048
#define NKG 512
#define NH 512
#define NH3 1536
#define NV 32000
#define NSTEPS 64
#define NTILES 40            // per b: 32 sent + 8 graph (64 keys each)
#define NBLK 256
#define NTHR 512

typedef unsigned long long u64;
typedef unsigned int u32;
typedef unsigned short u16;
typedef __attribute__((ext_vector_type(8))) short short8;
typedef __attribute__((ext_vector_type(4))) float f32x4;

__device__ __forceinline__ float bfu(u32 u){ return __uint_as_float(u << 16); }
__device__ __forceinline__ u16 f2bf(float f){
  u32 b = __float_as_uint(f);
  return (u16)((b + 0x7FFFu + ((b>>16)&1u)) >> 16);
}

// ---- one-time: pack W_out into bf16 MFMA B-fragment order (validated r4) ----
__global__ void k_packw(const float* __restrict__ W, u16* __restrict__ wp){
  long t = (long)blockIdx.x*256 + threadIdx.x;   // 6,144,000 total
  int lane = (int)(t & 63);
  long g = t >> 6;
  int kc = (int)(g % 48);
  int v16 = (int)(g / 48);
  int v = v16*16 + (lane&15);
  int k0 = kc*32 + (lane>>4)*8;
  const float4* src = (const float4*)(W + (size_t)v*NH3 + k0);
  float4 a = src[0], b = src[1];
  float vals[8] = {a.x,a.y,a.z,a.w,b.x,b.y,b.z,b.w};
  u16 o[8];
  #pragma unroll
  for (int i=0;i<8;i++) o[i] = f2bf(vals[i]);
  uint4 out;
  out.x = (u32)o[0] | ((u32)o[1]<<16);
  out.y = (u32)o[2] | ((u32)o[3]<<16);
  out.z = (u32)o[4] | ((u32)o[5]<<16);
  out.w = (u32)o[6] | ((u32)o[7]<<16);
  ((uint4*)wp)[t] = out;
}

// ---- once per launch: hdT, embT(BOS), barrier state --------------------------
__global__ void k_init(const float* __restrict__ enc, const float* __restrict__ emb,
                       double* __restrict__ hdT, double* __restrict__ embT,
                       u32* __restrict__ flags, u32* __restrict__ gen){
  int i = blockIdx.x*256 + threadIdx.x;   // 64x256 = 16384 = NB*NH
  int b = i>>9, k = i&511;
  hdT[k*NB + b]  = (double)enc[i];
  embT[k*NB + b] = (double)emb[NH + k];   // BOS token = 1
  if (i < NBLK) flags[i] = 0u;
  if (i == NBLK) *gen = 0u;
}

// ---- software grid barrier: flag array + generation (monotone) ---------------
__device__ __forceinline__ void gridbar(u32* flags, u32* gen, u32 g){
  __syncthreads();
  __threadfence();
  if (blockIdx.x == 0){
    int t = threadIdx.x;
    if (t >= 1 && t < NBLK){
      while (__hip_atomic_load(&flags[t], __ATOMIC_ACQUIRE, __HIP_MEMORY_SCOPE_AGENT) < g)
        __builtin_amdgcn_s_sleep(2);
    }
    __syncthreads();
    if (t == 0)
      __hip_atomic_store(gen, g, __ATOMIC_RELEASE, __HIP_MEMORY_SCOPE_AGENT);
  } else {
    if (threadIdx.x == 0){
      __hip_atomic_store(&flags[blockIdx.x], g, __ATOMIC_RELEASE, __HIP_MEMORY_SCOPE_AGENT);
      while (__hip_atomic_load(gen, __ATOMIC_ACQUIRE, __HIP_MEMORY_SCOPE_AGENT) < g)
        __builtin_amdgcn_s_sleep(2);
    }
    __syncthreads();
  }
}

// ---- the whole 64-step decode loop in ONE kernel -----------------------------
__global__ __launch_bounds__(NTHR) void k_mega(
  const float* __restrict__ sf, const float* __restrict__ gf,
  const float* __restrict__ emb,
  const float* __restrict__ Wa, const float* __restrict__ Wih,
  const float* __restrict__ Whh,
  const float* __restrict__ bih, const float* __restrict__ bhh,
  const float* __restrict__ Wout, const float* __restrict__ bout,
  const u16* __restrict__ wpack,
  double* hdT, double* embT, double* qd, double* gxd, double* ghd, double* xd,
  double* pc, double* pden, double* ptm, u16* apack,
  float* out, u32* flags, u32* gen, int usew)
{
  __shared__ alignas(16) char SM[65536];
  __shared__ double scale[NTILES];
  __shared__ double dent[2];
  __shared__ double mshare[2];
  __shared__ int s_cnt, s_bidx;
  int tid = threadIdx.x;
  int lane = tid & 63, wv = tid >> 6;
  u32 g = 0;

  for (int t = 0; t < NSTEPS; t++){
    // ================= phase 1: gates (fp64 GEMVs, r6-validated math) ========
    {
      float* Wlds = (float*)SM;                 // 16 rows x 512 f = 32 KB
      double* xls = (double*)(SM + 32768);      // 64 k x 32 b doubles = 16 KB
      for (int vb = blockIdx.x; vb < 224; vb += NBLK){
        const float* Wseg; const double* xg; int row0, typ;
        if (vb < 32){ Wseg = Wa;  row0 = vb*16;        xg = hdT;  typ = 0; }
        else if (vb < 128){ Wseg = Wih; row0 = (vb-32)*16;  xg = embT; typ = 1; }
        else { Wseg = Whh; row0 = (vb-128)*16; xg = hdT;  typ = 2; }
        { const float4* src = (const float4*)(Wseg + (size_t)row0*NH);
          float4* d4 = (float4*)Wlds;
          for (int j=tid; j<2048; j+=NTHR) d4[j] = src[j]; }
        int ol = tid>>5, b = tid&31;
        double acc = 0.0;
        for (int kc=0; kc<8; kc++){
          __syncthreads();
          for (int j=tid; j<2048; j+=NTHR) xls[j] = xg[(size_t)kc*2048 + j];
          __syncthreads();
          #pragma unroll 16
          for (int kk=0; kk<64; kk++)
            acc += (double)Wlds[ol*512 + kc*64 + kk] * xls[kk*32 + b];
        }
        int o = row0 + ol;
        if (typ==0) qd[(size_t)b*NH + o] = acc;
        else if (typ==1) gxd[(size_t)b*NH3 + o] = acc + (double)bih[o];
        else ghd[(size_t)b*NH3 + o] = acc + (double)bhh[o];
        __syncthreads();
      }
    }
    gridbar(flags, gen, ++g);

    // ================= phase 2: attention (wave per 64-key tile, fp64) =======
    {
      int gw = (blockIdx.x<<3) + wv;            // 2048 waves, 1280 jobs
      if (gw < 1280){
        int b, tile, K, tslot; const float* src;
        if (gw < 1024){ b = gw>>5; tile = gw&31; K = NKS; src = sf; tslot = b*NTILES + tile; }
        else { int jj = gw-1024; b = jj>>3; tile = jj&7; K = NKG; src = gf; tslot = b*NTILES + 32 + tile; }
        const float* base = src + ((size_t)b*K + (size_t)tile*64)*NH;
        double qv[8];
        { const double* qb = qd + (size_t)b*NH + lane*8;
          #pragma unroll
          for (int j=0;j<8;j++) qv[j] = qb[j]; }
        double my = 0.0;
        for (int r=0; r<64; r+=2){
          const float4* rA = (const float4*)(base + (size_t)r*NH) + lane*2;
          const float4* rB = (const float4*)(base + (size_t)(r+1)*NH) + lane*2;
          float4 a0=rA[0], a1=rA[1], b0=rB[0], b1=rB[1];
          double sA = (double)a0.x*qv[0]+(double)a0.y*qv[1]+(double)a0.z*qv[2]+(double)a0.w*qv[3]
                    + (double)a1.x*qv[4]+(double)a1.y*qv[5]+(double)a1.z*qv[6]+(double)a1.w*qv[7];
          double sB = (double)b0.x*qv[0]+(double)b0.y*qv[1]+(double)b0.z*qv[2]+(double)b0.w*qv[3]
                    + (double)b1.x*qv[4]+(double)b1.y*qv[5]+(double)b1.z*qv[6]+(double)b1.w*qv[7];
          #pragma unroll
          for (int off=32; off>=1; off>>=1){ sA += __shfl_xor(sA, off); sB += __shfl_xor(sB, off); }
          if (lane == r)   my = sA;
          if (lane == r+1) my = sB;
        }
        double m = my;
        #pragma unroll
        for (int off=32; off>=1; off>>=1) m = fmax(m, __shfl_xor(m, off));
        double w = exp(my - m);
        double den = w;
        #pragma unroll
        for (int off=32; off>=1; off>>=1) den += __shfl_xor(den, off);
        if (lane==0){ pden[tslot] = den; ptm[tslot] = m; }
        double acc[8] = {0,0,0,0,0,0,0,0};
        for (int r=0; r<64; r++){
          double wr = __shfl(w, r);
          const float4* rr = (const float4*)(base + (size_t)r*NH) + lane*2;
          float4 v0 = rr[0], v1 = rr[1];
          acc[0]+=wr*(double)v0.x; acc[1]+=wr*(double)v0.y;
          acc[2]+=wr*(double)v0.z; acc[3]+=wr*(double)v0.w;
          acc[4]+=wr*(double)v1.x; acc[5]+=wr*(double)v1.y;
          acc[6]+=wr*(double)v1.z; acc[7]+=wr*(double)v1.w;
        }
        double* po = pc + (size_t)tslot*NH + lane*8;
        #pragma unroll
        for (int j=0;j<8;j++) po[j] = acc[j];
      }
    }
    gridbar(flags, gen, ++g);

    // ================= phase 3: merge + GRU + x/apack (r7-validated math) ====
    if (blockIdx.x < 32){
      int b = blockIdx.x;
      int i = tid;                              // 0..511 = full NH
      if (tid==0){
        double ms = -1e300, mg = -1e300;
        for (int q=0;q<32;q++)       ms = fmax(ms, ptm[b*NTILES+q]);
        for (int q=32;q<NTILES;q++)  mg = fmax(mg, ptm[b*NTILES+q]);
        mshare[0] = ms; mshare[1] = mg;
      }
      __syncthreads();
      if (tid < NTILES){
        double mm = (tid<32) ? mshare[0] : mshare[1];
        scale[tid] = exp(ptm[b*NTILES+tid] - mm);
      }
      __syncthreads();
      if (tid==0){
        double ds = 0.0, dg = 0.0;
        for (int q=0;q<32;q++)      ds += pden[b*NTILES+q]*scale[q];
        for (int q=32;q<NTILES;q++) dg += pden[b*NTILES+q]*scale[q];
        dent[0] = ds; dent[1] = dg;
      }
      __syncthreads();
      double cs = 0.0, cg = 0.0;
      for (int q=0;q<32;q++)      cs += pc[(size_t)(b*NTILES+q)*NH + i]*scale[q];
      for (int q=32;q<NTILES;q++) cg += pc[(size_t)(b*NTILES+q)*NH + i]*scale[q];
      cs /= dent[0]; cg /= dent[1];
      double xr = gxd[(size_t)b*NH3 + i],        hr = ghd[(size_t)b*NH3 + i];
      double xz = gxd[(size_t)b*NH3 + NH + i],   hz = ghd[(size_t)b*NH3 + NH + i];
      double xn = gxd[(size_t)b*NH3 + 2*NH + i], hn = ghd[(size_t)b*NH3 + 2*NH + i];
      double r = 1.0/(1.0+exp(-(xr+hr)));
      double z = 1.0/(1.0+exp(-(xz+hz)));
      double nn = tanh(xn + r*hn);
      double hold = hdT[(size_t)i*NB + b];
      double hnew = (1.0 - z)*nn + z*hold;
      hdT[(size_t)i*NB + b] = hnew;
      int mt = b>>4, row = b&15;
      double vals[3] = {hnew, cg, cs};
      #pragma unroll
      for (int c=0;c<3;c++){
        int col = c*NH + i;
        xd[(size_t)b*NH3 + col] = vals[c];
        int kc = col>>5, kg = (col&31)>>3, j = col&7;
        int ln = row + 16*kg;
        size_t base = ((size_t)(mt*48+kc)*64 + ln)*8 + j;
        float xf = (float)vals[c];
        u16 hi = f2bf(xf);
        float rem = (float)(vals[c] - (double)bfu((u32)hi));
        apack[base] = hi;
        apack[base + (size_t)2*48*64*8] = f2bf(rem);
      }
    }
    gridbar(flags, gen, ++g);

    // ================= phase 4: bulk logits ==================================
    float* dst = out + (size_t)t*NB*NV;
    if (usew){
      for (int vb = blockIdx.x; vb < 250; vb += NBLK){
        int v16 = vb*8 + wv;                    // 2000 tiles
        const short8* bp = (const short8*)wpack + (size_t)v16*48*64 + lane;
        const short8* ap = (const short8*)apack + lane;
        f32x4 acc0 = {0.f,0.f,0.f,0.f}, acc1 = {0.f,0.f,0.f,0.f};
        #pragma unroll 4
        for (int kc=0; kc<48; kc++){
          short8 bf = bp[(size_t)kc*64];
          short8 a0h = ap[(size_t)kc*64];
          short8 a1h = ap[(size_t)(48+kc)*64];
          short8 a0l = ap[(size_t)(96+kc)*64];
          short8 a1l = ap[(size_t)(144+kc)*64];
          acc0 = __builtin_amdgcn_mfma_f32_16x16x32_bf16(a0h, bf, acc0, 0, 0, 0);
          acc0 = __builtin_amdgcn_mfma_f32_16x16x32_bf16(a0l, bf, acc0, 0, 0, 0);
          acc1 = __builtin_amdgcn_mfma_f32_16x16x32_bf16(a1h, bf, acc1, 0, 0, 0);
          acc1 = __builtin_amdgcn_mfma_f32_16x16x32_bf16(a1l, bf, acc1, 0, 0, 0);
        }
        int col = v16*16 + (lane&15);
        float bias = bout[col];
        int r0 = (lane>>4)*4;
        #pragma unroll
        for (int r=0;r<4;r++){
          int b0 = r0 + r;
          dst[(size_t)b0*NV + col] = acc0[r] + bias;
          dst[(size_t)(16+b0)*NV + col] = acc1[r] + bias;
        }
      }
    } else {
      float4* xs4 = (float4*)SM;                // 64 KB chunk staging
      for (int vb = blockIdx.x; vb < 250; vb += NBLK){
        int bg = tid>>6;
        int vbase = vb*128;
        int v0 = vbase + lane, v1 = vbase + 64 + lane;
        float acc0[4]={0,0,0,0}, acc1[4]={0,0,0,0};
        for (int c=0;c<3;c++){
          int kb = c*NH;
          __syncthreads();
          for (int i2=tid; i2<NB*128; i2+=NTHR){
            int b=i2>>7, kk=i2&127;
            float4 tt;
            tt.x = (float)xd[(size_t)b*NH3 + kb + kk*4+0];
            tt.y = (float)xd[(size_t)b*NH3 + kb + kk*4+1];
            tt.z = (float)xd[(size_t)b*NH3 + kb + kk*4+2];
            tt.w = (float)xd[(size_t)b*NH3 + kb + kk*4+3];
            xs4[i2] = tt;
          }
          __syncthreads();
          const float4* w0 = (const float4*)(Wout + (size_t)v0*NH3 + kb);
          const float4* w1 = (const float4*)(Wout + (size_t)v1*NH3 + kb);
          for (int k4=0;k4<128;k4++){
            float4 a = w0[k4], bb = w1[k4];
            #pragma unroll
            for (int j=0;j<4;j++){
              float4 xv = xs4[(bg*4+j)*128 + k4];
              acc0[j] += a.x*xv.x;  acc0[j] += a.y*xv.y;  acc0[j] += a.z*xv.z;  acc0[j] += a.w*xv.w;
              acc1[j] += bb.x*xv.x; acc1[j] += bb.y*xv.y; acc1[j] += bb.z*xv.z; acc1[j] += bb.w*xv.w;
            }
          }
        }
        float b0 = bout[v0], b1 = bout[v1];
        #pragma unroll
        for (int j=0;j<4;j++){
          int b = bg*4+j;
          dst[(size_t)b*NV + v0] = acc0[j]+b0;
          dst[(size_t)b*NV + v1] = acc1[j]+b1;
        }
        __syncthreads();
      }
    }
    gridbar(flags, gen, ++g);

    // ================= phase 5: fp64 argmax refine + embT ====================
    if (blockIdx.x < 32){
      int b = blockIdx.x;
      double* xs   = (double*)SM;               // 12 KB
      int*    cand = (int*)(SM + 12288);        // 8 KB
      double* cval = (double*)(SM + 20480);     // 16 KB
      float*  mred = (float*)(SM + 36864);      // 2 KB
      for (int i=tid;i<NH3;i+=NTHR) xs[i] = xd[(size_t)b*NH3 + i];
      const float4* lg = (const float4*)(dst + (size_t)b*NV);
      float mx = -1e30f;
      for (int i=tid; i<NV/4; i+=NTHR){
        float4 v = lg[i];
        mx = fmaxf(mx, fmaxf(fmaxf(v.x,v.y), fmaxf(v.z,v.w)));
      }
      mred[tid] = mx; __syncthreads();
      for (int s=NTHR/2;s>0;s>>=1){ if (tid<s) mred[tid] = fmaxf(mred[tid], mred[tid+s]); __syncthreads(); }
      float maxv = mred[0];
      float margin = 1.0f;
      for (int attempt=0; attempt<2; attempt++){
        if (tid==0) s_cnt = 0;
        __syncthreads();
        float thr = maxv - margin;
        for (int i=tid; i<NV/4; i+=NTHR){
          float4 v = lg[i];
          if (v.x>thr){ int p=atomicAdd(&s_cnt,1); if(p<2048) cand[p]=i*4+0; }
          if (v.y>thr){ int p=atomicAdd(&s_cnt,1); if(p<2048) cand[p]=i*4+1; }
          if (v.z>thr){ int p=atomicAdd(&s_cnt,1); if(p<2048) cand[p]=i*4+2; }
          if (v.w>thr){ int p=atomicAdd(&s_cnt,1); if(p<2048) cand[p]=i*4+3; }
        }
        __syncthreads();
        if (s_cnt <= 2048) break;
        margin = 0.125f;
        __syncthreads();
      }
      int n = min(s_cnt, 2048);
      for (int c=wv; c<n; c+=8){
        int v = cand[c];
        const float4* wr = (const float4*)(Wout + (size_t)v*NH3);
        double a = 0.0;
        #pragma unroll
        for (int i=0;i<6;i++){
          int e = lane + 64*i;
          float4 w4 = wr[e];
          a += (double)w4.x*xs[e*4+0] + (double)w4.y*xs[e*4+1]
             + (double)w4.z*xs[e*4+2] + (double)w4.w*xs[e*4+3];
        }
        #pragma unroll
        for (int off=32; off>=1; off>>=1) a += __shfl_xor(a, off);
        if (lane==0){
          double av = a + (double)bout[v];
          cval[c] = av;
          dst[(size_t)b*NV + v] = (float)av;
        }
      }
      __syncthreads();
      if (tid==0){
        double bv = -1e300; int bi = 0x7fffffff;
        for (int c=0;c<n;c++){
          if (cval[c] > bv || (cval[c] == bv && cand[c] < bi)){ bv = cval[c]; bi = cand[c]; }
        }
        s_bidx = bi;
      }
      __syncthreads();
      int bi = s_bidx;
      for (int k=tid; k<NH; k+=NTHR)
        embT[(size_t)k*NB + b] = (double)emb[(size_t)bi*NH + k];
    }
    gridbar(flags, gen, ++g);
  }
}

extern "C" void kernel_launch(void* const* d_in, const int* in_sizes, int n_in,
                              void* d_out, int out_size, void* d_ws, size_t ws_size,
                              hipStream_t stream) {
  const float* sent  = (const float*)d_in[0];
  const float* graph = (const float*)d_in[1];
  const float* enc   = (const float*)d_in[2];
  const float* Wa    = (const float*)d_in[3];
  const float* emb   = (const float*)d_in[4];
  const float* Wih   = (const float*)d_in[5];
  const float* Whh   = (const float*)d_in[6];
  const float* bih   = (const float*)d_in[7];
  const float* bhh   = (const float*)d_in[8];
  const float* Wout  = (const float*)d_in[9];
  const float* bout  = (const float*)d_in[10];
  float* out = (float*)d_out;

  char* wsb = (char*)d_ws;
  size_t off = 0;
  auto allocd = [&](size_t n)->double*{ double* p = (double*)(wsb + off); off += n*8; return p; };
  double* hdT = allocd(NB*NH);
  double* embT= allocd(NB*NH);
  double* qd  = allocd(NB*NH);
  double* gxd = allocd((size_t)NB*NH3);
  double* ghd = allocd((size_t)NB*NH3);
  double* xd  = allocd((size_t)NB*NH3);
  double* pc  = allocd((size_t)NB*NTILES*NH);
  double* pden= allocd(NB*NTILES);
  double* ptm = allocd(NB*NTILES);
  u16* apack = (u16*)(wsb + off); off += (size_t)4*48*64*8*2*2;  // hi+lo blocks
  u32* flags = (u32*)(wsb + off); off += (NBLK+8)*4;
  u32* gen   = flags + NBLK;

  size_t wpoff = (off + 255) & ~(size_t)255;
  const size_t WPBYTES = (size_t)2000*48*64*16;   // 98,304,000
  int usew = (ws_size >= wpoff + WPBYTES) ? 1 : 0;
  u16* wpack = (u16*)(wsb + wpoff);

  if (usew) k_packw<<<dim3(24000), dim3(256), 0, stream>>>(Wout, wpack);
  k_init<<<dim3(64), dim3(256), 0, stream>>>(enc, emb, hdT, embT, flags, gen);

  k_mega<<<dim3(NBLK), dim3(NTHR), 0, stream>>>(
      sent, graph, emb, Wa, Wih, Whh, bih, bhh, Wout, bout, wpack,
      hdT, embT, qd, gxd, ghd, xd, pc, pden, ptm, apack,
      out, flags, gen, usew);
}

// Round 9
// 24920.522 us; speedup vs baseline: 4.0907x; 4.0907x over previous
//
#include <hip/hip_runtime.h>
#include <hip/hip_bf16.h>
#include <math.h>

#define NB 32
#define NKS 2048
#define NKG 512
#define NH 512
#define NH3 1536
#define NV 32000
#define NSTEPS 64
#define NTILES 80            // per b: 64 sent + 16 graph tiles (32 keys each)

typedef unsigned long long u64;
typedef unsigned int u32;
typedef unsigned short u16;
typedef __attribute__((ext_vector_type(8))) short short8;
typedef __attribute__((ext_vector_type(4))) float f32x4;

__device__ __forceinline__ float bfu(u32 u){ return __uint_as_float(u << 16); }
__device__ __forceinline__ u16 f2bf(float f){
  u32 b = __float_as_uint(f);
  return (u16)((b + 0x7FFFu + ((b>>16)&1u)) >> 16);
}

// ---- one-time: pack W_out into bf16 MFMA B-fragment order (validated r4) ----
__global__ void k_packw(const float* __restrict__ W, u16* __restrict__ wp){
  long t = (long)blockIdx.x*256 + threadIdx.x;   // 6,144,000 total
  int lane = (int)(t & 63);
  long g = t >> 6;
  int kc = (int)(g % 48);
  int v16 = (int)(g / 48);
  int v = v16*16 + (lane&15);
  int k0 = kc*32 + (lane>>4)*8;
  const float4* src = (const float4*)(W + (size_t)v*NH3 + k0);
  float4 a = src[0], b = src[1];
  float vals[8] = {a.x,a.y,a.z,a.w,b.x,b.y,b.z,b.w};
  u16 o[8];
  #pragma unroll
  for (int i=0;i<8;i++) o[i] = f2bf(vals[i]);
  uint4 out;
  out.x = (u32)o[0] | ((u32)o[1]<<16);
  out.y = (u32)o[2] | ((u32)o[3]<<16);
  out.z = (u32)o[4] | ((u32)o[5]<<16);
  out.w = (u32)o[6] | ((u32)o[7]<<16);
  ((uint4*)wp)[t] = out;
}

// ---- once per launch: hdT[k][b] = enc, embT[k][b] = emb[BOS] ---------------
__global__ void k_init(const float* __restrict__ enc, const float* __restrict__ emb,
                       double* __restrict__ hdT, double* __restrict__ embT){
  int i = blockIdx.x*256 + threadIdx.x;   // 64x256 = 16384 = NB*NH
  int b = i>>9, k = i&511;
  hdT[k*NB + b]  = (double)enc[i];
  embT[k*NB + b] = (double)emb[NH + k];   // BOS token = 1
}

// ---- per step (fp64): q = Wa@h, gx = Wih@emb+b, gh = Whh@h+b (validated r6) -
__global__ __launch_bounds__(256) void k_gates(
    const double* __restrict__ hdT, const double* __restrict__ embT,
    const float* __restrict__ Wa, const float* __restrict__ Wih,
    const float* __restrict__ Whh,
    const float* __restrict__ bih, const float* __restrict__ bhh,
    double* __restrict__ qd, double* __restrict__ gxd, double* __restrict__ ghd)
{
  __shared__ float Wlds[8*512];            // 16 KB
  __shared__ double xls[64*NB];            // 16 KB per k-chunk
  int blk = blockIdx.x, tid = threadIdx.x;
  const float* Wseg; const double* xg; int row0;
  if (blk < 64){ Wseg = Wa; row0 = blk*8; xg = hdT; }
  else if (blk < 256){ Wseg = Wih; row0 = (blk-64)*8; xg = embT; }
  else { Wseg = Whh; row0 = (blk-256)*8; xg = hdT; }
  { const float4* src = (const float4*)(Wseg + (size_t)row0*NH);
    float4* d4 = (float4*)Wlds;
    for (int j=tid; j<1024; j+=256) d4[j] = src[j]; }
  int ol = tid>>5, b = tid&31;
  double acc = 0.0;
  for (int kc=0; kc<8; kc++){
    __syncthreads();
    for (int j=tid; j<64*NB; j+=256) xls[j] = xg[(size_t)kc*64*NB + j];
    __syncthreads();
    #pragma unroll 16
    for (int kk=0; kk<64; kk++)
      acc += (double)Wlds[ol*512 + kc*64 + kk] * xls[kk*NB + b];
  }
  if (blk < 64){
    qd[(size_t)b*NH + row0 + ol] = acc;
  } else if (blk < 256){
    int o = row0 + ol;
    gxd[(size_t)b*NH3 + o] = acc + (double)bih[o];
  } else {
    int o = row0 + ol;
    ghd[(size_t)b*NH3 + o] = acc + (double)bhh[o];
  }
}

// ---- per step: ONE-PASS fp64 attention, online softmax, rows in registers ---
// grid 640 x 256: wave = one 32-key tile. 2048 sent-waves + 512 graph-waves.
__global__ __launch_bounds__(256) void k_att(
  const float* __restrict__ sf, const float* __restrict__ gf,
  const double* __restrict__ qd,
  double* __restrict__ pc, double* __restrict__ pden, double* __restrict__ ptm)
{
  int gw = blockIdx.x*4 + (threadIdx.x>>6);
  int lane = threadIdx.x & 63;
  int b, tslot; const float* base;
  if (gw < 2048){ b = gw>>6; int tile = gw&63;
    base = sf + ((size_t)b*NKS + (size_t)tile*32)*NH; tslot = b*NTILES + tile; }
  else { int jj = gw-2048; b = jj>>4; int tg = jj&15;
    base = gf + ((size_t)b*NKG + (size_t)tg*32)*NH; tslot = b*NTILES + 64 + tg; }
  double qv[8];
  { const double* qb = qd + (size_t)b*NH + lane*8;
    #pragma unroll
    for (int j=0;j<8;j++) qv[j] = qb[j]; }
  double m = -1.0e300, den = 0.0;
  double acc[8] = {0,0,0,0,0,0,0,0};
  for (int r=0; r<32; r+=4){
    const float4* r0p = (const float4*)(base + (size_t)r*NH) + lane*2;
    const float4* r1p = (const float4*)(base + (size_t)(r+1)*NH) + lane*2;
    const float4* r2p = (const float4*)(base + (size_t)(r+2)*NH) + lane*2;
    const float4* r3p = (const float4*)(base + (size_t)(r+3)*NH) + lane*2;
    float4 a0=r0p[0], a1=r0p[1], b0=r1p[0], b1=r1p[1];
    float4 c0=r2p[0], c1=r2p[1], d0=r3p[0], d1=r3p[1];
    double sA = (double)a0.x*qv[0]+(double)a0.y*qv[1]+(double)a0.z*qv[2]+(double)a0.w*qv[3]
              + (double)a1.x*qv[4]+(double)a1.y*qv[5]+(double)a1.z*qv[6]+(double)a1.w*qv[7];
    double sB = (double)b0.x*qv[0]+(double)b0.y*qv[1]+(double)b0.z*qv[2]+(double)b0.w*qv[3]
              + (double)b1.x*qv[4]+(double)b1.y*qv[5]+(double)b1.z*qv[6]+(double)b1.w*qv[7];
    double sC = (double)c0.x*qv[0]+(double)c0.y*qv[1]+(double)c0.z*qv[2]+(double)c0.w*qv[3]
              + (double)c1.x*qv[4]+(double)c1.y*qv[5]+(double)c1.z*qv[6]+(double)c1.w*qv[7];
    double sD = (double)d0.x*qv[0]+(double)d0.y*qv[1]+(double)d0.z*qv[2]+(double)d0.w*qv[3]
              + (double)d1.x*qv[4]+(double)d1.y*qv[5]+(double)d1.z*qv[6]+(double)d1.w*qv[7];
    #pragma unroll
    for (int off=32; off>=1; off>>=1){
      sA += __shfl_xor(sA, off); sB += __shfl_xor(sB, off);
      sC += __shfl_xor(sC, off); sD += __shfl_xor(sD, off);
    }
    double mn = fmax(fmax(fmax(sA,sB), fmax(sC,sD)), m);
    if (mn > m){                     // wave-uniform (reduced values identical)
      double sc_ = exp(m - mn);      // first iter: exp(-huge) = 0
      den *= sc_;
      #pragma unroll
      for (int j=0;j<8;j++) acc[j] *= sc_;
      m = mn;
    }
    double wA = exp(sA - m), wB = exp(sB - m);
    double wC = exp(sC - m), wD = exp(sD - m);
    den += (wA + wB) + (wC + wD);
    acc[0] += wA*(double)a0.x + wB*(double)b0.x + wC*(double)c0.x + wD*(double)d0.x;
    acc[1] += wA*(double)a0.y + wB*(double)b0.y + wC*(double)c0.y + wD*(double)d0.y;
    acc[2] += wA*(double)a0.z + wB*(double)b0.z + wC*(double)c0.z + wD*(double)d0.z;
    acc[3] += wA*(double)a0.w + wB*(double)b0.w + wC*(double)c0.w + wD*(double)d0.w;
    acc[4] += wA*(double)a1.x + wB*(double)b1.x + wC*(double)c1.x + wD*(double)d1.x;
    acc[5] += wA*(double)a1.y + wB*(double)b1.y + wC*(double)c1.y + wD*(double)d1.y;
    acc[6] += wA*(double)a1.z + wB*(double)b1.z + wC*(double)c1.z + wD*(double)d1.z;
    acc[7] += wA*(double)a1.w + wB*(double)b1.w + wC*(double)c1.w + wD*(double)d1.w;
  }
  if (lane==0){ pden[tslot] = den; ptm[tslot] = m; }
  double* po = pc + (size_t)tslot*NH + lane*8;
  #pragma unroll
  for (int j=0;j<8;j++) po[j] = acc[j];
}

// ---- per step (fp64): merge 80 tiles, GRU, x + hdT + split-bf16 frags -------
__global__ __launch_bounds__(256) void k_comb(
  const double* __restrict__ pc, const double* __restrict__ pden,
  const double* __restrict__ ptm,
  const double* __restrict__ gxd, const double* __restrict__ ghd,
  double* __restrict__ hdT, double* __restrict__ xd, u16* __restrict__ apack)
{
  int b = blockIdx.x, half = blockIdx.y, tid = threadIdx.x;
  int i = half*256 + tid;
  __shared__ double scale[NTILES];
  __shared__ double dent[2];
  __shared__ double mshare[2];
  if (tid==0){
    double ms = -1e300, mg = -1e300;
    for (int t=0;t<64;t++)       ms = fmax(ms, ptm[b*NTILES+t]);
    for (int t=64;t<NTILES;t++)  mg = fmax(mg, ptm[b*NTILES+t]);
    mshare[0] = ms; mshare[1] = mg;
  }
  __syncthreads();
  if (tid < NTILES){
    double mm = (tid<64) ? mshare[0] : mshare[1];
    scale[tid] = exp(ptm[b*NTILES+tid] - mm);
  }
  __syncthreads();
  if (tid==0){
    double ds = 0.0, dg = 0.0;
    for (int t=0;t<64;t++)      ds += pden[b*NTILES+t]*scale[t];
    for (int t=64;t<NTILES;t++) dg += pden[b*NTILES+t]*scale[t];
    dent[0] = ds; dent[1] = dg;
  }
  __syncthreads();
  double cs = 0.0, cg = 0.0;
  for (int t=0;t<64;t++)      cs += pc[(size_t)(b*NTILES+t)*NH + i]*scale[t];
  for (int t=64;t<NTILES;t++) cg += pc[(size_t)(b*NTILES+t)*NH + i]*scale[t];
  cs /= dent[0]; cg /= dent[1];
  double xr = gxd[(size_t)b*NH3 + i],        hr = ghd[(size_t)b*NH3 + i];
  double xz = gxd[(size_t)b*NH3 + NH + i],   hz = ghd[(size_t)b*NH3 + NH + i];
  double xn = gxd[(size_t)b*NH3 + 2*NH + i], hn = ghd[(size_t)b*NH3 + 2*NH + i];
  double r = 1.0/(1.0+exp(-(xr+hr)));
  double z = 1.0/(1.0+exp(-(xz+hz)));
  double nn = tanh(xn + r*hn);
  double hold = hdT[(size_t)i*NB + b];
  double hnew = (1.0 - z)*nn + z*hold;
  hdT[(size_t)i*NB + b] = hnew;
  int mt = b>>4, row = b&15;
  double vals[3] = {hnew, cg, cs};
  #pragma unroll
  for (int c=0;c<3;c++){
    int col = c*NH + i;
    xd[(size_t)b*NH3 + col] = vals[c];
    int kc = col>>5, kg = (col&31)>>3, j = col&7;
    int lane = row + 16*kg;
    size_t base = ((size_t)(mt*48+kc)*64 + lane)*8 + j;
    float xf = (float)vals[c];
    u16 hi = f2bf(xf);
    float rem = (float)(vals[c] - (double)bfu((u32)hi));
    apack[base] = hi;
    apack[base + (size_t)2*48*64*8] = f2bf(rem);   // lo block after hi block
  }
}

// --------- per step: logits via split-bf16 MFMA; store-only (validated) ------
__global__ __launch_bounds__(256) void k_logv(
  const u16* __restrict__ apack, const u16* __restrict__ wpack,
  const float* __restrict__ bout, float* __restrict__ dst)
{
  int tid = threadIdx.x;
  int wv = tid>>6, lane = tid&63;
  int v16 = blockIdx.x*4 + wv;                    // 500 blocks -> 2000 tiles
  const short8* bp = (const short8*)wpack + (size_t)v16*48*64 + lane;
  const short8* ap = (const short8*)apack + lane;
  f32x4 acc0 = {0.f,0.f,0.f,0.f}, acc1 = {0.f,0.f,0.f,0.f};
  #pragma unroll 4
  for (int kc=0; kc<48; kc++){
    short8 bf = bp[(size_t)kc*64];
    short8 a0h = ap[(size_t)kc*64];
    short8 a1h = ap[(size_t)(48+kc)*64];
    short8 a0l = ap[(size_t)(96+kc)*64];
    short8 a1l = ap[(size_t)(144+kc)*64];
    acc0 = __builtin_amdgcn_mfma_f32_16x16x32_bf16(a0h, bf, acc0, 0, 0, 0);
    acc0 = __builtin_amdgcn_mfma_f32_16x16x32_bf16(a0l, bf, acc0, 0, 0, 0);
    acc1 = __builtin_amdgcn_mfma_f32_16x16x32_bf16(a1h, bf, acc1, 0, 0, 0);
    acc1 = __builtin_amdgcn_mfma_f32_16x16x32_bf16(a1l, bf, acc1, 0, 0, 0);
  }
  int col = v16*16 + (lane&15);
  float bias = bout[col];
  int r0 = (lane>>4)*4;
  #pragma unroll
  for (int r=0;r<4;r++){
    int b0 = r0 + r;
    dst[(size_t)b0*NV + col] = acc0[r] + bias;
    dst[(size_t)(16+b0)*NV + col] = acc1[r] + bias;
  }
}

// ---- per step: self-scanned max, fp64 argmax refinement, embT (validated r7)
__global__ __launch_bounds__(256) void k_refine(
  float* __restrict__ logits, const double* __restrict__ xd,
  const float* __restrict__ Wout, const float* __restrict__ bout,
  const float* __restrict__ emb, double* __restrict__ embT)
{
  int b = blockIdx.x, tid = threadIdx.x;
  __shared__ double xs[NH3];          // 12 KB
  for (int i=tid;i<NH3;i+=256) xs[i] = xd[(size_t)b*NH3 + i];
  const float4* lg = (const float4*)(logits + (size_t)b*NV);
  float mx = -1e30f;
  for (int i=tid; i<NV/4; i+=256){
    float4 v = lg[i];
    mx = fmaxf(mx, fmaxf(fmaxf(v.x,v.y), fmaxf(v.z,v.w)));
  }
  __shared__ float mred[256];
  mred[tid] = mx; __syncthreads();
  for (int s=128;s>0;s>>=1){ if (tid<s) mred[tid] = fmaxf(mred[tid], mred[tid+s]); __syncthreads(); }
  float maxv = mred[0];
  __shared__ int cnt;
  __shared__ int cand[2048];          // 8 KB
  __shared__ double cval[2048];       // 16 KB
  float margin = 1.0f;
  for (int attempt=0; attempt<2; attempt++){
    if (tid==0) cnt = 0;
    __syncthreads();
    float thr = maxv - margin;
    for (int i=tid; i<NV/4; i+=256){
      float4 v = lg[i];
      if (v.x>thr){ int p=atomicAdd(&cnt,1); if(p<2048) cand[p]=i*4+0; }
      if (v.y>thr){ int p=atomicAdd(&cnt,1); if(p<2048) cand[p]=i*4+1; }
      if (v.z>thr){ int p=atomicAdd(&cnt,1); if(p<2048) cand[p]=i*4+2; }
      if (v.w>thr){ int p=atomicAdd(&cnt,1); if(p<2048) cand[p]=i*4+3; }
    }
    __syncthreads();
    if (cnt <= 2048) break;
    margin = 0.125f;                  // bulk err << 0.125, true argmax still included
    __syncthreads();
  }
  int n = min(cnt, 2048);
  int wv = tid>>6, lane = tid&63;
  for (int c=wv; c<n; c+=4){
    int v = cand[c];
    const float4* wr = (const float4*)(Wout + (size_t)v*NH3);
    double a = 0.0;
    #pragma unroll
    for (int i=0;i<6;i++){
      int e = lane + 64*i;
      float4 w4 = wr[e];
      a += (double)w4.x*xs[e*4+0] + (double)w4.y*xs[e*4+1]
         + (double)w4.z*xs[e*4+2] + (double)w4.w*xs[e*4+3];
    }
    #pragma unroll
    for (int off=32; off>=1; off>>=1) a += __shfl_xor(a, off);
    if (lane==0){
      double av = a + (double)bout[v];
      cval[c] = av;
      logits[(size_t)b*NV + v] = (float)av;
    }
  }
  __syncthreads();
  __shared__ int bidx;
  if (tid==0){
    double bv = -1e300; int bi = 0x7fffffff;
    for (int c=0;c<n;c++){
      if (cval[c] > bv || (cval[c] == bv && cand[c] < bi)){ bv = cval[c]; bi = cand[c]; }
    }
    bidx = bi;
  }
  __syncthreads();
  int bi = bidx;
  for (int k=tid; k<NH; k+=256)
    embT[(size_t)k*NB + b] = (double)emb[(size_t)bi*NH + k];
}

// -------- fp32 fallback bulk logits (used only if ws can't hold packed W) ----
__global__ __launch_bounds__(256) void k_logits(
  const double* __restrict__ xd, const float* __restrict__ Wout,
  const float* __restrict__ bout, float* __restrict__ dst)
{
  __shared__ float4 xs4[NB*128];
  int tid = threadIdx.x;
  int bg = tid>>6, lane = tid&63;
  int vbase = blockIdx.x*128;
  int v0 = vbase + lane, v1 = vbase + 64 + lane;
  float acc0[8] = {0.f,0.f,0.f,0.f,0.f,0.f,0.f,0.f};
  float acc1[8] = {0.f,0.f,0.f,0.f,0.f,0.f,0.f,0.f};
  for (int c=0;c<3;c++){
    int kb = c*NH;
    for (int i=tid;i<NB*128;i+=256){
      int b=i>>7, kk=i&127;
      float4 t;
      t.x = (float)xd[(size_t)b*NH3 + kb + kk*4+0];
      t.y = (float)xd[(size_t)b*NH3 + kb + kk*4+1];
      t.z = (float)xd[(size_t)b*NH3 + kb + kk*4+2];
      t.w = (float)xd[(size_t)b*NH3 + kb + kk*4+3];
      xs4[i] = t;
    }
    __syncthreads();
    const float4* w0 = (const float4*)(Wout + (size_t)v0*NH3 + kb);
    const float4* w1 = (const float4*)(Wout + (size_t)v1*NH3 + kb);
    for (int k4=0;k4<128;k4++){
      float4 a = w0[k4], bb = w1[k4];
      #pragma unroll
      for (int j=0;j<8;j++){
        float4 xv = xs4[(bg*8+j)*128 + k4];
        acc0[j] += a.x*xv.x;  acc0[j] += a.y*xv.y;  acc0[j] += a.z*xv.z;  acc0[j] += a.w*xv.w;
        acc1[j] += bb.x*xv.x; acc1[j] += bb.y*xv.y; acc1[j] += bb.z*xv.z; acc1[j] += bb.w*xv.w;
      }
    }
    __syncthreads();
  }
  float b0 = bout[v0], b1 = bout[v1];
  #pragma unroll
  for (int j=0;j<8;j++){
    int b = bg*8+j;
    dst[(size_t)b*NV + v0] = acc0[j]+b0;
    dst[(size_t)b*NV + v1] = acc1[j]+b1;
  }
}

extern "C" void kernel_launch(void* const* d_in, const int* in_sizes, int n_in,
                              void* d_out, int out_size, void* d_ws, size_t ws_size,
                              hipStream_t stream) {
  const float* sent  = (const float*)d_in[0];
  const float* graph = (const float*)d_in[1];
  const float* enc   = (const float*)d_in[2];
  const float* Wa    = (const float*)d_in[3];
  const float* emb   = (const float*)d_in[4];
  const float* Wih   = (const float*)d_in[5];
  const float* Whh   = (const float*)d_in[6];
  const float* bih   = (const float*)d_in[7];
  const float* bhh   = (const float*)d_in[8];
  const float* Wout  = (const float*)d_in[9];
  const float* bout  = (const float*)d_in[10];
  float* out = (float*)d_out;

  char* wsb = (char*)d_ws;
  size_t off = 0;
  auto allocd = [&](size_t n)->double*{ double* p = (double*)(wsb + off); off += n*8; return p; };
  double* hdT = allocd(NB*NH);
  double* embT= allocd(NB*NH);
  double* qd  = allocd(NB*NH);
  double* gxd = allocd((size_t)NB*NH3);
  double* ghd = allocd((size_t)NB*NH3);
  double* xd  = allocd((size_t)NB*NH3);
  double* pc  = allocd((size_t)NB*NTILES*NH);
  double* pden= allocd(NB*NTILES);
  double* ptm = allocd(NB*NTILES);
  u16* apack = (u16*)(wsb + off); off += (size_t)4*48*64*8*2;  // hi+lo blocks

  size_t wpoff = (off + 255) & ~(size_t)255;
  const size_t WPBYTES = (size_t)2000*48*64*16;   // 98,304,000
  int usew = (ws_size >= wpoff + WPBYTES) ? 1 : 0;
  u16* wpack = (u16*)(wsb + wpoff);

  if (usew) k_packw<<<dim3(24000), dim3(256), 0, stream>>>(Wout, wpack);
  k_init<<<dim3(64), dim3(256), 0, stream>>>(enc, emb, hdT, embT);

  for (int t=0; t<NSTEPS; t++){
    k_gates<<<dim3(448), dim3(256), 0, stream>>>(hdT, embT, Wa, Wih, Whh, bih, bhh,
                                                 qd, gxd, ghd);
    k_att<<<dim3(640), dim3(256), 0, stream>>>(sent, graph, qd, pc, pden, ptm);
    k_comb<<<dim3(32,2), dim3(256), 0, stream>>>(pc, pden, ptm, gxd, ghd, hdT, xd, apack);
    float* dst = out + (size_t)t*NB*NV;
    if (usew){
      k_logv<<<dim3(500), dim3(256), 0, stream>>>(apack, wpack, bout, dst);
    } else {
      k_logits<<<dim3(250), dim3(256), 0, stream>>>(xd, Wout, bout, dst);
    }
    k_refine<<<dim3(32), dim3(256), 0, stream>>>(dst, xd, Wout, bout, emb, embT);
  }
}